// Round 12
// baseline (43.281 us; speedup 1.0000x reference)
//
#include <hip/hip_runtime.h>
#include <hip/hip_bf16.h>
#include <math.h>

namespace {

constexpr int L   = 64;    // steps
constexpr int NH  = 256;   // nhid
constexpr int NC  = 64;    // cache_N
constexpr int BSZ = 32;

typedef float f32x4 __attribute__((ext_vector_type(4)));
typedef short bf16x8 __attribute__((ext_vector_type(8)));   // 8 bf16 in 4 VGPRs

// Split 8 fp32 into hi/lo bf16x8: x = hi + lo + O(2^-18 x). (validated R3-R11)
__device__ inline void split8(const float4 x0, const float4 x1,
                              bf16x8& hi, bf16x8& lo) {
  float f[8];
  *(float4*)(f)     = x0;
  *(float4*)(f + 4) = x1;
#pragma unroll
  for (int q = 0; q < 8; ++q) {
    const __hip_bfloat16 h = __float2bfloat16(f[q]);        // RNE
    unsigned short hu;
    __builtin_memcpy(&hu, &h, 2);
    const float hf = __builtin_bit_cast(float, (unsigned)hu << 16);
    const __hip_bfloat16 l = __float2bfloat16(f[q] - hf);   // exact residual, RNE
    unsigned short lu;
    __builtin_memcpy(&lu, &l, 2);
    hi[q] = (short)hu;
    lo[q] = (short)lu;
  }
}

// global -> LDS direct: per-lane 16B source, dest = uniform base + lane*16
__device__ inline void gl16(const void* g, void* l) {
  __builtin_amdgcn_global_load_lds(
      (const __attribute__((address_space(1))) unsigned*)(g),
      (__attribute__((address_space(3))) unsigned*)(l), 16, 0, 0);
}

// Fragment bijection (16x16x32, shared k-map for A and B):
//   lane l, elem i -> row = tile*16 + (l&15),
//                     k   = kc*32 + (i>>2)*16 + ((l>>4)&3)*4 + (i&3)
// Valid because only max(C) is consumed (row maps of A and B independent;
// k maps must agree — they do by construction on both sides).

// ws: [0,2MB) Q frag images (64KB per b): hi [0,32K), lo [32K,64K);
// slot s = (it*8 + kc)*64 + l.
__global__ __launch_bounds__(256) void qsplit_kernel(
    const float* __restrict__ query, char* __restrict__ ws) {
  const int X = blockIdx.x;           // 256 blocks: b = X>>3, s-group = X&7
  const int b = X >> 3;
  const int s = (X & 7) * 256 + threadIdx.x;   // 0..2047
  const int it = s >> 9;
  const int kc = (s >> 6) & 7;
  const int l  = s & 63;
  const int row = it * 16 + (l & 15);
  const int col = kc * 32 + ((l >> 4) & 3) * 4;
  const float* src = query + ((size_t)row * BSZ + b) * NH + col;
  bf16x8 hi, lo;
  split8(*(const float4*)src, *(const float4*)(src + 16), hi, lo);
  char* wb = ws + (size_t)b * 65536;
  *(bf16x8*)(wb + (size_t)s * 16)         = hi;
  *(bf16x8*)(wb + 32768 + (size_t)s * 16) = lo;
}

// Block = 256 thr = 4 waves, one (b,n). The 64KB K strip is staged into LDS
// with STRICTLY SEQUENTIAL 1KB windows (one gl16 per row; lane-permuted
// source chunk^(row&7), linear dest -> XOR-swizzled image; reads apply the
// same XOR: 2-way banks only). Wave w = it owns C rows [w*16,w*16+16):
// A-frags live in 64 VGPR (from ws), B-frags split from LDS per (jt,kc).
__global__ __launch_bounds__(256, 2) void attmax_mfma(
    const float* __restrict__ keys,    // (64, 32, 16384)
    const char* __restrict__ ws,
    float* __restrict__ out)           // out[b*64+n] = att
{
  __shared__ __align__(16) char klds[64 * 1024];
  __shared__ float wm[4];

  // grid 2048: b = X&31 -> same-b blocks share XCD (X%8 == b%8)
  const unsigned X = blockIdx.x;
  const int b = X & 31;
  const int n = X >> 5;

  const int tid  = threadIdx.x;
  const int w    = tid >> 6;          // wave = it
  const int lane = tid & 63;

  const float* kb = keys + ((size_t)n * BSZ + b) * (size_t)(L * NH);

  // ---- Stage K strip: wave w rows [w*16, w*16+16) = 16KB sequential ----
#pragma unroll
  for (int jj = 0; jj < 16; ++jj) {
    const int j = w * 16 + jj;
    const char* src = (const char*)(kb + (size_t)j * NH) + ((lane ^ (j & 7)) * 16);
    gl16(src, klds + j * 1024);
  }

  // ---- A-frags for it=w from ws (lane-linear 16B loads, L2/L3-warm) ----
  bf16x8 ah[8], al[8];
  {
    const char* wb = ws + (size_t)b * 65536;
#pragma unroll
    for (int kc = 0; kc < 8; ++kc) {
      const int slot = ((w * 8 + kc) * 64 + lane) * 16;
      ah[kc] = *(const bf16x8*)(wb + slot);
      al[kc] = *(const bf16x8*)(wb + 32768 + slot);
    }
  }

  asm volatile("s_waitcnt vmcnt(0)" ::: "memory");
  __builtin_amdgcn_sched_barrier(0);
  __syncthreads();

  // ---- Compute: all jt, kc for it=w; B split from swizzled LDS ----
  const int rl = lane & 15;
  const int q4 = ((lane >> 4) & 3);
  const int sw = lane & 7;            // row&7 (row = jt*16 + rl, jt*16%8==0)

  f32x4 acc[4];
#pragma unroll
  for (int jt = 0; jt < 4; ++jt)
#pragma unroll
    for (int e = 0; e < 4; ++e) acc[jt][e] = 0.f;

#pragma unroll
  for (int jt = 0; jt < 4; ++jt) {
    const char* rowb = klds + (jt * 16 + rl) * 1024;
#pragma unroll
    for (int kc = 0; kc < 8; ++kc) {
      const float4 x0 = *(const float4*)(rowb + (((kc * 8 + q4) ^ sw) * 16));
      const float4 x1 = *(const float4*)(rowb + (((kc * 8 + 4 + q4) ^ sw) * 16));
      bf16x8 bh, bl;
      split8(x0, x1, bh, bl);
      acc[jt] = __builtin_amdgcn_mfma_f32_16x16x32_bf16(al[kc], bh, acc[jt], 0, 0, 0);
      acc[jt] = __builtin_amdgcn_mfma_f32_16x16x32_bf16(ah[kc], bl, acc[jt], 0, 0, 0);
      acc[jt] = __builtin_amdgcn_mfma_f32_16x16x32_bf16(ah[kc], bh, acc[jt], 0, 0, 0);
    }
  }

  // ---- Reduce: wave max -> block max -> out ----
  float m = -INFINITY;
#pragma unroll
  for (int jt = 0; jt < 4; ++jt)
#pragma unroll
    for (int e = 0; e < 4; ++e) m = fmaxf(m, acc[jt][e]);
#pragma unroll
  for (int off = 1; off < 64; off <<= 1)
    m = fmaxf(m, __shfl_xor(m, off, 64));

  if (lane == 0) wm[w] = m;
  __syncthreads();
  if (tid == 0)
    out[(size_t)b * NC + n] =
        fmaxf(fmaxf(wm[0], wm[1]), fmaxf(wm[2], wm[3]));
}

// One block (64 lanes) per batch b: 8 rounds of argmax with lowest-index
// tie-break (matches jax.lax.top_k stability). Indices written as floats.
__global__ __launch_bounds__(64) void topk_kernel(float* __restrict__ out) {
  const int b = blockIdx.x;
  const int l = threadIdx.x;
  float v = out[b * NC + l];
#pragma unroll
  for (int k = 0; k < 8; ++k) {
    float bv = v;
    int bi = l;
#pragma unroll
    for (int off = 1; off < 64; off <<= 1) {
      const float ov = __shfl_xor(bv, off, 64);
      const int oi = __shfl_xor(bi, off, 64);
      if (ov > bv || (ov == bv && oi < bi)) { bv = ov; bi = oi; }
    }
    if (l == 0) out[BSZ * NC + k * BSZ + b] = (float)bi;  // (topk, bsz) layout
    if (l == bi) v = -INFINITY;
  }
}

}  // namespace

extern "C" void kernel_launch(void* const* d_in, const int* in_sizes, int n_in,
                              void* d_out, int out_size, void* d_ws, size_t ws_size,
                              hipStream_t stream) {
  const float* query = (const float*)d_in[0];
  const float* keys  = (const float*)d_in[1];
  // d_in[2] (values) is dead code in the max_pooling branch — never read.
  float* out = (float*)d_out;
  char*  ws  = (char*)d_ws;   // 2 MB Q frag images

  qsplit_kernel<<<dim3(256), dim3(256), 0, stream>>>(query, ws);
  attmax_mfma<<<dim3(2048), dim3(256), 0, stream>>>(keys, ws, out);
  topk_kernel<<<dim3(BSZ), dim3(64), 0, stream>>>(out);
}